// Round 11
// baseline (236.432 us; speedup 1.0000x reference)
//
#include <hip/hip_runtime.h>

// VarianceLoss via one-hot MFMA segment reduction.  B=8, C=4, H=W=1024, NSEG=65.
//
// R11: ONE ROUND PER BLOCK.  R4-R10 showed per-wave software pipelining is
// defeated by the compiler (loads re-sunk, VGPR pinned ~40) and 4 waves/SIMD
// cannot hide the ~2K-cyc per-round latency (R7 MODE3: even bare
// loads+softmax is 60% idle).  So: gridx=1024 -> 8192 blocks, each doing a
// single 1024-px round straight-line (load, softmax, stage, kt x8, reduce,
// atomics).  19KB LDS -> 8 resident blocks/CU = 8 waves/SIMD, and block
// turnover keeps the CU supplied with waves at different phases -- the
// hardware dispatcher does the pipelining software couldn't.
//
// Numerics unchanged since R3 (absmax 0.0): one-hot A built from staged seg
// ids (3 packed u16 ops per 2 k-slots); B = bf16 hi+lo split payload
// {p0,p1,p2,qq} + const-1 cnt col via cndmask; hi+lo merged in epilogue;
// p3 recovered at finalize as cnt-s0-s1-s2.

typedef unsigned short u16x2 __attribute__((ext_vector_type(2)));
typedef unsigned int   u32x4 __attribute__((ext_vector_type(4)));
typedef short          s16x8 __attribute__((ext_vector_type(8)));   // 8 x bf16
typedef float          f32x4 __attribute__((ext_vector_type(4)));

constexpr int   B_    = 8;
constexpr int   SEGS  = 64;      // segments 1..64 (segment 0 masked out by ref)
constexpr int   VALS  = 5;       // p0,p1,p2,qq,cnt
constexpr float EPS_  = 1e-8f;

constexpr int PLANE   = 528;               // bytes per plane (512 + bank skew)
constexpr int NSLOT   = 9;                 // hi0,lo0,hi1,lo1,hi2,lo2,hi3,lo3,seg
constexpr int WLDS    = NSLOT * PLANE;     // 4752 B per wave
constexpr int LDS_SZ  = (4 * WLDS > 16384) ? 4 * WLDS : 16384;   // 19008

__device__ __forceinline__ unsigned asu(float f)  { return __float_as_uint(f); }
__device__ __forceinline__ float    asf(unsigned u){ return __uint_as_float(u); }

__global__ __launch_bounds__(256) void vl_accum(const float* __restrict__ logit,
                                                const int*   __restrict__ inst,
                                                float* __restrict__ accOut,
                                                int N)
{
    __shared__ __align__(16) unsigned char lds[LDS_SZ];

    const int tid  = threadIdx.x;
    const int wid  = tid >> 6;
    const int lane = tid & 63;
    const int col  = lane & 15;
    const int quad = lane >> 4;
    const int wbase = wid * WLDS;

    // B-read plane per column: slot 2c = hi_c, 2c+1 = lo_c (c = 0..3), 8 = seg
    const bool selLds = (col < 4) | (col >= 8 && col < 12);
    const unsigned cword = (col == 4) ? 0x3F803F80u : 0u;   // cnt hi = 1.0
    const int pl = (col < 4) ? (2 * col)
                 : ((col >= 8 && col < 12) ? (2 * (col - 8) + 1) : 0);
    const int bRd   = wbase + pl * PLANE + quad * 16;   // + kt*64
    const int segRd = wbase + 8 * PLANE + quad * 16;    // + kt*64
    const int segWr = wbase + 8 * PLANE + lane * 8;

    u16x2 rowdup[4];
#pragma unroll
    for (int t = 0; t < 4; ++t) {
        unsigned short rw = (unsigned short)(t * 16 + col);
        rowdup[t] = (u16x2){rw, rw};
    }
    const u16x2 one2  = (u16x2){1, 1};
    const u16x2 negb  = (u16x2){0xC080, 0xC080};   // -0x3F80 mod 2^16
    const u16x2 posb  = (u16x2){0x3F80, 0x3F80};

    const int b = blockIdx.y;
    const float* __restrict__ l0 = logit + (size_t)b * 4 * N;
    const int*   __restrict__ ib = inst  + (size_t)b * N;

    // ---- single round: load 4 px/thread ----
    const int q  = (blockIdx.x << 10) + (tid << 2);
    const bool ok = (q + 4 <= N);
    const int qc = ok ? q : 0;

    float4 x0 = *(const float4*)(l0 + qc);
    float4 x1 = *(const float4*)(l0 + (size_t)N     + qc);
    float4 x2 = *(const float4*)(l0 + (size_t)2 * N + qc);
    float4 x3 = *(const float4*)(l0 + (size_t)3 * N + qc);
    int4   sg = *(const int4*)(ib + qc);
    if (!ok) sg = make_int4(0, 0, 0, 0);   // seg 0 -> no row, dropped

    const float c0[4] = {x0.x, x0.y, x0.z, x0.w};
    const float c1[4] = {x1.x, x1.y, x1.z, x1.w};
    const float c2[4] = {x2.x, x2.y, x2.z, x2.w};
    const float c3[4] = {x3.x, x3.y, x3.z, x3.w};

    float P0[4], P1[4], P2[4], QQ[4];
#pragma unroll
    for (int i = 0; i < 4; ++i) {
        float va = c0[i], vb = c1[i], vc = c2[i], vd = c3[i];
        float m  = fmaxf(fmaxf(va, vb), fmaxf(vc, vd));
        float e0 = __expf(va - m);
        float e1 = __expf(vb - m);
        float e2 = __expf(vc - m);
        float e3 = __expf(vd - m);
        float rr = 1.0f / (e0 + e1 + e2 + e3);
        float q0 = e0 * rr, q1 = e1 * rr, q2 = e2 * rr, q3 = e3 * rr;
        P0[i] = q0; P1[i] = q1; P2[i] = q2;
        QQ[i] = q0*q0 + q1*q1 + q2*q2 + q3*q3;
    }

    // ---- stage: hi (truncated bf16) to slot 2P, lo residual to 2P+1 ----
#define STAGE_PLANE(P, ARR)                                                     \
    {                                                                           \
        unsigned a0 = asu(ARR[0]), a1 = asu(ARR[1]);                            \
        unsigned a2 = asu(ARR[2]), a3 = asu(ARR[3]);                            \
        unsigned h1m = a1 & 0xFFFF0000u, h3m = a3 & 0xFFFF0000u;                \
        unsigned hi01 = (a0 >> 16) | h1m;                                       \
        unsigned hi23 = (a2 >> 16) | h3m;                                       \
        float l0f = ARR[0] - asf(a0 & 0xFFFF0000u);                             \
        float l1f = ARR[1] - asf(h1m);                                          \
        float l2f = ARR[2] - asf(a2 & 0xFFFF0000u);                             \
        float l3f = ARR[3] - asf(h3m);                                          \
        unsigned lo01 = (asu(l0f) >> 16) | (asu(l1f) & 0xFFFF0000u);            \
        unsigned lo23 = (asu(l2f) >> 16) | (asu(l3f) & 0xFFFF0000u);            \
        *(uint2*)(lds + wbase + (2*(P)) * PLANE + lane * 8)   = make_uint2(hi01, hi23); \
        *(uint2*)(lds + wbase + (2*(P)+1) * PLANE + lane * 8) = make_uint2(lo01, lo23); \
    }
    STAGE_PLANE(0, P0)
    STAGE_PLANE(1, P1)
    STAGE_PLANE(2, P2)
    STAGE_PLANE(3, QQ)
#undef STAGE_PLANE

    // seg-1 as u16 (seg 0 / invalid -> 0xFFFF, matches no row)
    {
        unsigned r0 = (unsigned)(sg.x - 1) & 0xFFFFu;
        unsigned r1 = (unsigned)(sg.y - 1) & 0xFFFFu;
        unsigned r2 = (unsigned)(sg.z - 1) & 0xFFFFu;
        unsigned r3 = (unsigned)(sg.w - 1) & 0xFFFFu;
        *(uint2*)(lds + segWr) = make_uint2(r0 | (r1 << 16), r2 | (r3 << 16));
    }
    // own-wave RAW through LDS: compiler inserts lgkmcnt waits.

    f32x4 acc0a = {0,0,0,0}, acc1a = {0,0,0,0}, acc2a = {0,0,0,0}, acc3a = {0,0,0,0};
    f32x4 acc0b = {0,0,0,0}, acc1b = {0,0,0,0}, acc2b = {0,0,0,0}, acc3b = {0,0,0,0};

#pragma unroll
    for (int kt = 0; kt < 8; ++kt) {
        s16x8 braw = *(const s16x8*)(lds + bRd   + kt * 64);
        u32x4 sv   = *(const u32x4*)(lds + segRd + kt * 64);
        u32x4 bw   = __builtin_bit_cast(u32x4, braw);
#pragma unroll
        for (int i = 0; i < 4; ++i) bw[i] = selLds ? bw[i] : cword;
        s16x8 bfrag = __builtin_bit_cast(s16x8, bw);

#define DO_TILE(T, ACC)                                                         \
        {                                                                       \
            u32x4 fr;                                                           \
            _Pragma("unroll")                                                   \
            for (int i = 0; i < 4; ++i) {                                       \
                u16x2 sp  = __builtin_bit_cast(u16x2, sv[i]);                   \
                u16x2 d   = sp - rowdup[T];                                     \
                u16x2 mn  = __builtin_elementwise_min(d, one2);                 \
                u16x2 f   = mn * negb + posb;  /* 0x3F80 or 0 */                \
                fr[i] = __builtin_bit_cast(unsigned, f);                        \
            }                                                                   \
            s16x8 afrag = __builtin_bit_cast(s16x8, fr);                        \
            ACC = __builtin_amdgcn_mfma_f32_16x16x32_bf16(afrag, bfrag, ACC, 0, 0, 0); \
        }
        if ((kt & 1) == 0) {
            DO_TILE(0, acc0a) DO_TILE(1, acc1a) DO_TILE(2, acc2a) DO_TILE(3, acc3a)
        } else {
            DO_TILE(0, acc0b) DO_TILE(1, acc1b) DO_TILE(2, acc2b) DO_TILE(3, acc3b)
        }
#undef DO_TILE
    }

    // merge even/odd-kt accumulator halves
    f32x4 acc0 = acc0a + acc0b;
    f32x4 acc1 = acc1a + acc1b;
    f32x4 acc2 = acc2a + acc2b;
    f32x4 acc3 = acc3a + acc3b;

    // ---- cross-wave reduce + global atomics (aliases staging LDS) ----
    __syncthreads();                       // all waves done reading their planes
    float* cl = (float*)lds;               // [w][t][lane][reg] f32 = 16 KB
    {
        const int base = ((wid * 4) * 64 + lane) * 4;
        *(f32x4*)(cl + base)            = acc0;
        *(f32x4*)(cl + base + 64 * 4)   = acc1;
        *(f32x4*)(cl + base + 128 * 4)  = acc2;
        *(f32x4*)(cl + base + 192 * 4)  = acc3;
    }
    __syncthreads();

    for (int i = tid; i < SEGS * VALS; i += 256) {
        const int row = i / VALS;          // 0..63  (= seg-1)
        const int cc  = i - row * VALS;    // 0..4
        const int t   = row >> 4;
        const int rr  = row & 15;
        const int g   = rr >> 2;
        const int reg = rr & 3;
        const int lhi = g * 16 + cc;
        const int llo = lhi + 8;
        float v = 0.0f;
#pragma unroll
        for (int w = 0; w < 4; ++w) {
            v += cl[((w * 4 + t) * 64 + lhi) * 4 + reg];
            v += cl[((w * 4 + t) * 64 + llo) * 4 + reg];
        }
        unsafeAtomicAdd(accOut + ((size_t)blockIdx.y * SEGS + row) * VALS + cc, v);
    }
}

__global__ __launch_bounds__(256) void vl_finalize(const float* __restrict__ acc,
                                                   float* __restrict__ out)
{
    __shared__ float sum_var[B_];
    __shared__ float num_ids[B_];
    if (threadIdx.x < B_) { sum_var[threadIdx.x] = 0.0f; num_ids[threadIdx.x] = 0.0f; }
    __syncthreads();

    for (int i = threadIdx.x; i < B_ * SEGS; i += 256) {
        const float* a = acc + (size_t)i * VALS;
        const int b = i >> 6;
        const float cnt = a[4];
        if (cnt > 1.0f) {
            const float inv_n = 1.0f / cnt;       // n_safe = cnt (cnt > 0)
            const float denom = cnt - 1.0f;       // cnt > 1
            const float s0 = a[0], s1 = a[1], s2 = a[2];
            const float s3 = cnt - s0 - s1 - s2;  // p's sum to 1 per pixel
            const float ssum2 = s0*s0 + s1*s1 + s2*s2 + s3*s3;
            const float sv = (a[3] - ssum2 * inv_n) / denom;
            atomicAdd(&sum_var[b], sv);
        }
        if (cnt > 0.0f) atomicAdd(&num_ids[b], 1.0f);
    }
    __syncthreads();

    if (threadIdx.x == 0) {
        float loss = 0.0f;
#pragma unroll
        for (int b = 0; b < B_; ++b) loss += sum_var[b] / (num_ids[b] + EPS_);
        out[0] = loss / (float)B_;
    }
}

extern "C" void kernel_launch(void* const* d_in, const int* in_sizes, int n_in,
                              void* d_out, int out_size, void* d_ws, size_t ws_size,
                              hipStream_t stream) {
    const float* logit = (const float*)d_in[0];
    const int*   inst  = (const int*)d_in[1];
    float* out = (float*)d_out;
    float* acc = (float*)d_ws;                      // B_*SEGS*VALS f32 = 10240 B

    const int totalPix = in_sizes[1];               // B*H*W
    const int N = totalPix / B_;                    // H*W per batch

    hipMemsetAsync(acc, 0, (size_t)B_ * SEGS * VALS * sizeof(float), stream);

    const int gridx = (N + 1023) >> 10;             // 1024 px per block, 1 round
    dim3 grid(gridx, B_);
    vl_accum<<<grid, 256, 0, stream>>>(logit, inst, acc, N);
    vl_finalize<<<1, 256, 0, stream>>>(acc, out);
}

// Round 12
// 219.358 us; speedup vs baseline: 1.0778x; 1.0778x over previous
//
#include <hip/hip_runtime.h>

// VarianceLoss via one-hot MFMA segment reduction.  B=8, C=4, H=W=1024, NSEG=65.
//
// R12: R10 structure (best, 219us: double-buffered staging, loads issued at
// round top, kt loop on previous round's buffer) + ASM-FORCED batched LDS
// reads.  R4-R11 showed the compiler collapses every C-level read batch /
// prefetch (VGPR pinned ~40) leaving 8 exposed ~120cyc ds-waits per round.
// Inline-asm ds_read_b128 quarters with counted lgkmcnt waits (T3/T4 pattern)
// cannot be collapsed:
//   issue Q0,Q1 (8 reads) -> lgkmcnt(4) -> compute kt0,kt1 -> issue Q2
//   -> lgkmcnt(4) -> compute kt2,kt3 -> issue Q3 -> lgkmcnt(4) -> compute
//   kt4,kt5 -> lgkmcnt(0) -> compute kt6,kt7
// Counted waits are robust to the 9 outstanding stage-writes (in-order ds
// queue: wait(4) == "all but my last 4 reads done").  sched_barrier(0) after
// each wait per rule 18 (MFMA hoists past asm lgkmcnt otherwise).
//
// Numerics unchanged since R3 (absmax 0.0).

typedef unsigned short u16x2 __attribute__((ext_vector_type(2)));
typedef unsigned int   u32x4 __attribute__((ext_vector_type(4)));
typedef short          s16x8 __attribute__((ext_vector_type(8)));   // 8 x bf16
typedef float          f32x4 __attribute__((ext_vector_type(4)));

constexpr int   B_    = 8;
constexpr int   SEGS  = 64;      // segments 1..64 (segment 0 masked out by ref)
constexpr int   VALS  = 5;       // p0,p1,p2,qq,cnt
constexpr float EPS_  = 1e-8f;

constexpr int PLANE   = 528;               // bytes per plane (512 + bank skew)
constexpr int NSLOT   = 9;                 // hi0,lo0,hi1,lo1,hi2,lo2,hi3,lo3,seg
constexpr int BUFSZ   = NSLOT * PLANE;     // 4752 B per buffer
constexpr int WLDS    = 2 * BUFSZ;         // 9504 B per wave (double-buffered)
constexpr int LDS_SZ  = (4 * WLDS > 16384) ? 4 * WLDS : 16384;   // 38016

__device__ __forceinline__ unsigned asu(float f)  { return __float_as_uint(f); }
__device__ __forceinline__ float    asf(unsigned u){ return __uint_as_float(u); }

// issue 4 ds_read_b128: {B,S} at offset OA and {B,S} at offset OB
#define ISSUE_Q(BA, SA, BB, SB, OA, OB)                                         \
    asm volatile("ds_read_b128 %0, %4 offset:" #OA "\n\t"                       \
                 "ds_read_b128 %1, %5 offset:" #OA "\n\t"                       \
                 "ds_read_b128 %2, %4 offset:" #OB "\n\t"                       \
                 "ds_read_b128 %3, %5 offset:" #OB                              \
                 : "=&v"(BA), "=&v"(SA), "=&v"(BB), "=&v"(SB)                   \
                 : "v"(addrB), "v"(addrS));

#define WAITQ(N)                                                                \
    asm volatile("s_waitcnt lgkmcnt(" #N ")" ::: "memory");                     \
    __builtin_amdgcn_sched_barrier(0);

__global__ __launch_bounds__(256, 4) void vl_accum(const float* __restrict__ logit,
                                                   const int*   __restrict__ inst,
                                                   float* __restrict__ accOut,
                                                   int N, int ppb)
{
    __shared__ __align__(16) unsigned char lds[LDS_SZ];

    const int tid  = threadIdx.x;
    const int wid  = tid >> 6;
    const int lane = tid & 63;
    const int col  = lane & 15;
    const int quad = lane >> 4;
    const int wbase = wid * WLDS;

    const bool selLds = (col < 4) | (col >= 8 && col < 12);
    const unsigned cword = (col == 4) ? 0x3F803F80u : 0u;   // cnt hi = 1.0
    const int pl = (col < 4) ? (2 * col)
                 : ((col >= 8 && col < 12) ? (2 * (col - 8) + 1) : 0);
    const int bRd0   = wbase + pl * PLANE + quad * 16;   // + buf*BUFSZ + kt*64
    const int segRd0 = wbase + 8 * PLANE + quad * 16;    // + buf*BUFSZ + kt*64
    const int segWr0 = wbase + 8 * PLANE + lane * 8;     // + buf*BUFSZ

    u16x2 rowdup[4];
#pragma unroll
    for (int t = 0; t < 4; ++t) {
        unsigned short rw = (unsigned short)(t * 16 + col);
        rowdup[t] = (u16x2){rw, rw};
    }
    const u16x2 one2  = (u16x2){1, 1};
    const u16x2 negb  = (u16x2){0xC080, 0xC080};   // -0x3F80 mod 2^16
    const u16x2 posb  = (u16x2){0x3F80, 0x3F80};

    const int b = blockIdx.y;
    const float* __restrict__ l0 = logit + (size_t)b * 4 * N;
    const int*   __restrict__ ib = inst  + (size_t)b * N;

    f32x4 acc0 = {0,0,0,0}, acc1 = {0,0,0,0}, acc2 = {0,0,0,0}, acc3 = {0,0,0,0};

    const int blockStart = blockIdx.x * ppb;
    const int rounds = ppb >> 10;
    const int base0  = blockStart + (wid << 8) + (lane << 2);

#define LOAD_ROUND(R, X0, X1, X2, X3, SG)                                       \
    {                                                                           \
        const int q  = base0 + ((R) << 10);                                     \
        const bool ok = (q + 4 <= N);                                           \
        const int qc = ok ? q : 0;                                              \
        X0 = *(const float4*)(l0 + qc);                                         \
        X1 = *(const float4*)(l0 + (size_t)N     + qc);                         \
        X2 = *(const float4*)(l0 + (size_t)2 * N + qc);                         \
        X3 = *(const float4*)(l0 + (size_t)3 * N + qc);                         \
        int4 sgt = *(const int4*)(ib + qc);                                     \
        SG = ok ? sgt : make_int4(0, 0, 0, 0);                                  \
    }

#define SOFTMAX4(X0, X1, X2, X3, P0, P1, P2, QQ)                                \
    {                                                                           \
        const float sc0[4] = {X0.x, X0.y, X0.z, X0.w};                          \
        const float sc1[4] = {X1.x, X1.y, X1.z, X1.w};                          \
        const float sc2[4] = {X2.x, X2.y, X2.z, X2.w};                          \
        const float sc3[4] = {X3.x, X3.y, X3.z, X3.w};                          \
        _Pragma("unroll")                                                       \
        for (int i = 0; i < 4; ++i) {                                           \
            float va = sc0[i], vb = sc1[i], vc = sc2[i], vd = sc3[i];           \
            float m  = fmaxf(fmaxf(va, vb), fmaxf(vc, vd));                     \
            float e0 = __expf(va - m);                                          \
            float e1 = __expf(vb - m);                                          \
            float e2 = __expf(vc - m);                                          \
            float e3 = __expf(vd - m);                                          \
            float rr = 1.0f / (e0 + e1 + e2 + e3);                              \
            float q0 = e0 * rr, q1 = e1 * rr, q2 = e2 * rr, q3 = e3 * rr;       \
            P0[i] = q0; P1[i] = q1; P2[i] = q2;                                 \
            QQ[i] = q0*q0 + q1*q1 + q2*q2 + q3*q3;                              \
        }                                                                       \
    }

#define STAGE_PLANE(BOFF, P, ARR)                                               \
    {                                                                           \
        unsigned a0 = asu(ARR[0]), a1 = asu(ARR[1]);                            \
        unsigned a2 = asu(ARR[2]), a3 = asu(ARR[3]);                            \
        unsigned h1m = a1 & 0xFFFF0000u, h3m = a3 & 0xFFFF0000u;                \
        unsigned hi01 = (a0 >> 16) | h1m;                                       \
        unsigned hi23 = (a2 >> 16) | h3m;                                       \
        float l0f = ARR[0] - asf(a0 & 0xFFFF0000u);                             \
        float l1f = ARR[1] - asf(h1m);                                          \
        float l2f = ARR[2] - asf(a2 & 0xFFFF0000u);                             \
        float l3f = ARR[3] - asf(h3m);                                          \
        unsigned lo01 = (asu(l0f) >> 16) | (asu(l1f) & 0xFFFF0000u);            \
        unsigned lo23 = (asu(l2f) >> 16) | (asu(l3f) & 0xFFFF0000u);            \
        *(uint2*)(lds + (BOFF) + wbase + (2*(P)) * PLANE + lane * 8)   = make_uint2(hi01, hi23); \
        *(uint2*)(lds + (BOFF) + wbase + (2*(P)+1) * PLANE + lane * 8) = make_uint2(lo01, lo23); \
    }

#define STAGE_ALL(BOFF, P0, P1, P2, QQ, SG)                                     \
    {                                                                           \
        STAGE_PLANE(BOFF, 0, P0)                                                \
        STAGE_PLANE(BOFF, 1, P1)                                                \
        STAGE_PLANE(BOFF, 2, P2)                                                \
        STAGE_PLANE(BOFF, 3, QQ)                                                \
        unsigned r0 = (unsigned)(SG.x - 1) & 0xFFFFu;                           \
        unsigned r1 = (unsigned)(SG.y - 1) & 0xFFFFu;                           \
        unsigned r2 = (unsigned)(SG.z - 1) & 0xFFFFu;                           \
        unsigned r3 = (unsigned)(SG.w - 1) & 0xFFFFu;                           \
        *(uint2*)(lds + (BOFF) + segWr0) = make_uint2(r0 | (r1 << 16), r2 | (r3 << 16)); \
    }

    // one kt's worth of compute from registers BQ (payload) and SQ (seg ids)
#define COMPUTE_KT(BQ, SQ)                                                      \
    {                                                                           \
        u32x4 bw = BQ;                                                          \
        _Pragma("unroll")                                                       \
        for (int i = 0; i < 4; ++i) bw[i] = selLds ? bw[i] : cword;             \
        s16x8 bfrag = __builtin_bit_cast(s16x8, bw);                            \
        u32x4 sv = SQ;                                                          \
        DO_TILE(0, acc0) DO_TILE(1, acc1) DO_TILE(2, acc2) DO_TILE(3, acc3)     \
    }

#define DO_TILE(T, ACC)                                                         \
        {                                                                       \
            u32x4 fr;                                                           \
            _Pragma("unroll")                                                   \
            for (int i = 0; i < 4; ++i) {                                       \
                u16x2 sp  = __builtin_bit_cast(u16x2, sv[i]);                   \
                u16x2 d   = sp - rowdup[T];                                     \
                u16x2 mn  = __builtin_elementwise_min(d, one2);                 \
                u16x2 f   = mn * negb + posb;  /* 0x3F80 or 0 */                \
                fr[i] = __builtin_bit_cast(unsigned, f);                        \
            }                                                                   \
            s16x8 afrag = __builtin_bit_cast(s16x8, fr);                        \
            ACC = __builtin_amdgcn_mfma_f32_16x16x32_bf16(afrag, bfrag, ACC, 0, 0, 0); \
        }

    // ---- prologue: load+softmax+stage round 0 into buffer 0 ----
    if (rounds > 0) {
        float4 cx0, cx1, cx2, cx3; int4 csg;
        LOAD_ROUND(0, cx0, cx1, cx2, cx3, csg)
        float P0[4], P1[4], P2[4], QQ[4];
        SOFTMAX4(cx0, cx1, cx2, cx3, P0, P1, P2, QQ)
        STAGE_ALL(0, P0, P1, P2, QQ, csg)
    }

    for (int r = 0; r < rounds; ++r) {
        // issue next round's global loads; vmcnt wait lands at softmax below
        float4 nx0, nx1, nx2, nx3; int4 nsg;
        const bool hasNext = (r + 1 < rounds);
        if (hasNext) LOAD_ROUND(r + 1, nx0, nx1, nx2, nx3, nsg)
        __builtin_amdgcn_sched_barrier(0);

        // ---- kt pipeline on the buffer staged LAST round (asm-forced) ----
        const int bufOff = (r & 1) * BUFSZ;
        const unsigned addrB = (unsigned)(unsigned long long)(const void*)(lds + bufOff + bRd0);
        const unsigned addrS = (unsigned)(unsigned long long)(const void*)(lds + bufOff + segRd0);

        u32x4 b0, s0, b1, s1, b2, s2, b3, s3, b4, s4, b5, s5, b6, s6, b7, s7;
        ISSUE_Q(b0, s0, b1, s1, 0,   64)    // kt0, kt1
        ISSUE_Q(b2, s2, b3, s3, 128, 192)   // kt2, kt3
        WAITQ(4)                            // Q0 ready
        COMPUTE_KT(b0, s0)
        COMPUTE_KT(b1, s1)
        ISSUE_Q(b4, s4, b5, s5, 256, 320)   // kt4, kt5
        WAITQ(4)                            // Q1 ready
        COMPUTE_KT(b2, s2)
        COMPUTE_KT(b3, s3)
        ISSUE_Q(b6, s6, b7, s7, 384, 448)   // kt6, kt7
        WAITQ(4)                            // Q2 ready
        COMPUTE_KT(b4, s4)
        COMPUTE_KT(b5, s5)
        WAITQ(0)                            // Q3 ready
        COMPUTE_KT(b6, s6)
        COMPUTE_KT(b7, s7)

        // ---- softmax + stage round r+1 into the other buffer ----
        if (hasNext) {
            float P0[4], P1[4], P2[4], QQ[4];
            SOFTMAX4(nx0, nx1, nx2, nx3, P0, P1, P2, QQ)
            const int nOff = ((r + 1) & 1) * BUFSZ;
            STAGE_ALL(nOff, P0, P1, P2, QQ, nsg)
        }
    }
#undef DO_TILE
#undef COMPUTE_KT
#undef LOAD_ROUND
#undef SOFTMAX4
#undef STAGE_PLANE
#undef STAGE_ALL

    // ---- cross-wave reduce + global atomics (aliases staging LDS) ----
    __syncthreads();
    float* cl = (float*)lds;               // [w][t][lane][reg] f32 = 16 KB
    {
        const int base = ((wid * 4) * 64 + lane) * 4;
        *(f32x4*)(cl + base)            = acc0;
        *(f32x4*)(cl + base + 64 * 4)   = acc1;
        *(f32x4*)(cl + base + 128 * 4)  = acc2;
        *(f32x4*)(cl + base + 192 * 4)  = acc3;
    }
    __syncthreads();

    for (int i = tid; i < SEGS * VALS; i += 256) {
        const int row = i / VALS;          // 0..63  (= seg-1)
        const int cc  = i - row * VALS;    // 0..4
        const int t   = row >> 4;
        const int rr  = row & 15;
        const int g   = rr >> 2;
        const int reg = rr & 3;
        const int lhi = g * 16 + cc;
        const int llo = lhi + 8;
        float v = 0.0f;
#pragma unroll
        for (int w = 0; w < 4; ++w) {
            v += cl[((w * 4 + t) * 64 + lhi) * 4 + reg];
            v += cl[((w * 4 + t) * 64 + llo) * 4 + reg];
        }
        unsafeAtomicAdd(accOut + ((size_t)blockIdx.y * SEGS + row) * VALS + cc, v);
    }
}

__global__ __launch_bounds__(256) void vl_finalize(const float* __restrict__ acc,
                                                   float* __restrict__ out)
{
    __shared__ float sum_var[B_];
    __shared__ float num_ids[B_];
    if (threadIdx.x < B_) { sum_var[threadIdx.x] = 0.0f; num_ids[threadIdx.x] = 0.0f; }
    __syncthreads();

    for (int i = threadIdx.x; i < B_ * SEGS; i += 256) {
        const float* a = acc + (size_t)i * VALS;
        const int b = i >> 6;
        const float cnt = a[4];
        if (cnt > 1.0f) {
            const float inv_n = 1.0f / cnt;       // n_safe = cnt (cnt > 0)
            const float denom = cnt - 1.0f;       // cnt > 1
            const float s0 = a[0], s1 = a[1], s2 = a[2];
            const float s3 = cnt - s0 - s1 - s2;  // p's sum to 1 per pixel
            const float ssum2 = s0*s0 + s1*s1 + s2*s2 + s3*s3;
            const float sv = (a[3] - ssum2 * inv_n) / denom;
            atomicAdd(&sum_var[b], sv);
        }
        if (cnt > 0.0f) atomicAdd(&num_ids[b], 1.0f);
    }
    __syncthreads();

    if (threadIdx.x == 0) {
        float loss = 0.0f;
#pragma unroll
        for (int b = 0; b < B_; ++b) loss += sum_var[b] / (num_ids[b] + EPS_);
        out[0] = loss / (float)B_;
    }
}

extern "C" void kernel_launch(void* const* d_in, const int* in_sizes, int n_in,
                              void* d_out, int out_size, void* d_ws, size_t ws_size,
                              hipStream_t stream) {
    const float* logit = (const float*)d_in[0];
    const int*   inst  = (const int*)d_in[1];
    float* out = (float*)d_out;
    float* acc = (float*)d_ws;                      // B_*SEGS*VALS f32 = 10240 B

    const int totalPix = in_sizes[1];               // B*H*W
    const int N = totalPix / B_;                    // H*W per batch

    hipMemsetAsync(acc, 0, (size_t)B_ * SEGS * VALS * sizeof(float), stream);

    const int gridx = 128;                          // 1024 blocks = 4/CU (38KB LDS)
    int ppb = (N + gridx - 1) / gridx;
    ppb = (ppb + 1023) & ~1023;                     // 1024-px block rounds

    dim3 grid(gridx, B_);
    vl_accum<<<grid, 256, 0, stream>>>(logit, inst, acc, N, ppb);
    vl_finalize<<<1, 256, 0, stream>>>(acc, out);
}